// Round 1
// baseline (210.964 us; speedup 1.0000x reference)
//
#include <hip/hip_runtime.h>

#define LOG2E 1.44269504088896340736f
#define DM 1536
#define LL 2048
#define NN 16
#define NCHUNK 16
#define CLEN 128   // LL / NCHUNK

__device__ __forceinline__ float fexp2(float v) { return __builtin_amdgcn_exp2f(v); }
__device__ __forceinline__ float frcp(float v)  { return __builtin_amdgcn_rcpf(v); }

// Transpose B,C from [b][n][l] to [b][l>>2][n][l&3] so the scan threads can
// load float4 (4 consecutive timesteps) per state n with contiguous lanes.
__global__ void transpose_bc(const float* __restrict__ Bm, const float* __restrict__ Cm,
                             float* __restrict__ Bt, float* __restrict__ Ct) {
    int idx = blockIdx.x * 256 + threadIdx.x;       // 2*16*2048 = 65536 total
    int l  = idx & (LL - 1);
    int bn = idx >> 11;
    int b = bn >> 4, n = bn & (NN - 1);
    int o = ((b * (LL / 4) + (l >> 2)) * NN + n) * 4 + (l & 3);
    Bt[o] = Bm[idx];
    Ct[o] = Cm[idx];
}

// One block per (b,d). 256 threads = 16 chunks x 16 states.
// Phase 1: per-chunk local scan -> (P = prod deltaA, G = local h_end)
// Phase 2: serial compose over 16 chunks -> h_start per chunk
// Phase 3: re-run scan with correct h_start, reduce y over n, stage in LDS
// Phase 4: coalesced fused epilogue (y + x*D) * silu(z)
__global__ __launch_bounds__(256, 8) void ssm_scan(
    const float* __restrict__ x, const float* __restrict__ delta,
    const float* __restrict__ A, const float* __restrict__ Dv,
    const float* __restrict__ z, const float* __restrict__ Bt,
    const float* __restrict__ Ct, float* __restrict__ out)
{
    const int bd  = blockIdx.x;          // b*DM + d
    const int b   = bd / DM;
    const int d   = bd - b * DM;
    const int tid = threadIdx.x;
    const int c   = tid >> 4;            // chunk
    const int n   = tid & (NN - 1);      // state index

    __shared__ float Ps[NCHUNK][NN];
    __shared__ float Gs[NCHUNK][NN];
    __shared__ float Hs[NCHUNK][NN];
    __shared__ float ylds[LL];

    const float A2 = A[d * NN + n] * LOG2E;          // exp(dA) = exp2(d*A*log2e)
    const long  base = (long)bd * LL;
    const float* dp = delta + base + c * CLEN;
    const float* xp = x     + base + c * CLEN;
    // Bt layout: ((b*(LL/4) + l4)*NN + n)*4 + j ; for this thread l4 = c*32 + i/4
    const float* btq = Bt + ((long)(b * (LL / 4) + c * (CLEN / 4)) * NN + n) * 4;
    const float* ctq = Ct + ((long)(b * (LL / 4) + c * (CLEN / 4)) * NN + n) * 4;

    // ---- Phase 1: local scan with h0 = 0; track P = prod(a), G = local end state
    float p = 1.0f, g = 0.0f;
    for (int i = 0; i < CLEN; i += 4) {
        const float4 d4 = *(const float4*)(dp + i);
        const float4 x4 = *(const float4*)(xp + i);
        const float4 b4 = *(const float4*)(btq + i * NN);
        const float dd[4] = {d4.x, d4.y, d4.z, d4.w};
        const float xx[4] = {x4.x, x4.y, x4.z, x4.w};
        const float bb[4] = {b4.x, b4.y, b4.z, b4.w};
#pragma unroll
        for (int j = 0; j < 4; ++j) {
            const float a = fexp2(dd[j] * A2);
            g = __builtin_fmaf(a, g, dd[j] * xx[j] * bb[j]);
            p *= a;
        }
    }
    Ps[c][n] = p;
    Gs[c][n] = g;
    __syncthreads();

    // ---- Phase 2: compose chunk boundary states (16 serial steps, 16 threads)
    if (tid < NN) {
        float h = 0.0f;
#pragma unroll
        for (int cc = 0; cc < NCHUNK; ++cc) {
            Hs[cc][tid] = h;
            h = __builtin_fmaf(Ps[cc][tid], h, Gs[cc][tid]);
        }
    }
    __syncthreads();

    // ---- Phase 3: full scan with correct initial state, emit y per timestep
    float h = Hs[c][n];
    for (int i = 0; i < CLEN; i += 4) {
        const float4 d4 = *(const float4*)(dp + i);
        const float4 x4 = *(const float4*)(xp + i);
        const float4 b4 = *(const float4*)(btq + i * NN);
        const float4 c4 = *(const float4*)(ctq + i * NN);
        const float dd[4] = {d4.x, d4.y, d4.z, d4.w};
        const float xx[4] = {x4.x, x4.y, x4.z, x4.w};
        const float bb[4] = {b4.x, b4.y, b4.z, b4.w};
        const float cv[4] = {c4.x, c4.y, c4.z, c4.w};
#pragma unroll
        for (int j = 0; j < 4; ++j) {
            const float a = fexp2(dd[j] * A2);
            h = __builtin_fmaf(a, h, dd[j] * xx[j] * bb[j]);
            float yv = h * cv[j];
            // reduce over the 16 states (xor masks 1,2,4,8 stay in 16-lane group)
            yv += __shfl_xor(yv, 1);
            yv += __shfl_xor(yv, 2);
            yv += __shfl_xor(yv, 4);
            yv += __shfl_xor(yv, 8);
            if (n == 0) ylds[c * CLEN + i + j] = yv;
        }
    }
    __syncthreads();

    // ---- Phase 4: fused epilogue, fully coalesced float4
    const float Dd = Dv[d];
    const float* zp  = z + base;
    const float* xp2 = x + base;
    float* op = out + base;
#pragma unroll
    for (int r = 0; r < 2; ++r) {
        const int l0 = r * 1024 + tid * 4;
        const float4 y4 = *(const float4*)(&ylds[l0]);
        const float4 xv = *(const float4*)(xp2 + l0);
        const float4 zv = *(const float4*)(zp + l0);
        const float yy[4] = {y4.x, y4.y, y4.z, y4.w};
        const float xr[4] = {xv.x, xv.y, xv.z, xv.w};
        const float zz[4] = {zv.x, zv.y, zv.z, zv.w};
        float o[4];
#pragma unroll
        for (int j = 0; j < 4; ++j) {
            const float sig = frcp(1.0f + fexp2(-zz[j] * LOG2E));
            o[j] = (yy[j] + xr[j] * Dd) * (zz[j] * sig);
        }
        float4 o4 = {o[0], o[1], o[2], o[3]};
        *(float4*)(op + l0) = o4;
    }
}

extern "C" void kernel_launch(void* const* d_in, const int* in_sizes, int n_in,
                              void* d_out, int out_size, void* d_ws, size_t ws_size,
                              hipStream_t stream) {
    const float* x     = (const float*)d_in[0];
    const float* delta = (const float*)d_in[1];
    const float* A     = (const float*)d_in[2];
    const float* B     = (const float*)d_in[3];
    const float* C     = (const float*)d_in[4];
    const float* Dv    = (const float*)d_in[5];
    const float* z     = (const float*)d_in[6];
    float* out = (float*)d_out;

    float* Bt = (float*)d_ws;                  // 2*2048*16 floats = 256 KB
    float* Ct = Bt + 2 * LL * NN;              // next 256 KB

    transpose_bc<<<dim3((2 * NN * LL) / 256), dim3(256), 0, stream>>>(B, C, Bt, Ct);
    ssm_scan<<<dim3(2 * DM), dim3(256), 0, stream>>>(x, delta, A, Dv, z, Bt, Ct, out);
}